// Round 20
// baseline (48.654 us; speedup 1.0000x reference)
//
#include <hip/hip_runtime.h>

#define DD 40
#define SLM1 9
#define ANUM 268
#define MB 32
#define RST2 42   // red row stride (f32): all access groups <=2-way on banks

typedef __attribute__((ext_vector_type(8))) short short8;
typedef __attribute__((ext_vector_type(4))) float f32x4;
typedef __attribute__((ext_vector_type(16))) float f32x16;

// ws offsets (u16 units)
#define WS_LWF ((size_t)0)        // full tiles: (s*40+d)*1536 ; e=0..31 (32x32 B-frag)
#define WS_LWT ((size_t)552960)   // tail tiles: (s*10+t)*1536 ; col c -> d=4t+(c>>3), e=32+(c&7)
#define WS_QW  ((size_t)691200)   // s*3072 (+ et*1536)   (32x32 B-frag)
#define WS_MW  ((size_t)718848)   // s*3072 + et*1024 + kf*512  (16x16 B-frag)
#define WS_TW  ((size_t)746496)   // t*1536               (32x32 B-frag)

// lgkm-only barrier: drains LDS (cross-wave visibility) but lets global
// prefetch loads stay in flight across the barrier (T4-lite; __syncthreads
// would emit vmcnt(0) and stall every wave on the L2 round trip).
#define BAR_LDS() do { asm volatile("s_waitcnt lgkmcnt(0)" ::: "memory"); \
                       __builtin_amdgcn_s_barrier(); } while (0)

__device__ __forceinline__ unsigned short f2bf(float f){
  unsigned int u = __float_as_uint(f);
  u += 0x7FFFu + ((u >> 16) & 1u);
  return (unsigned short)(u >> 16);
}
__device__ __forceinline__ float relu6f(float v){
  return fminf(fmaxf(v, 0.0f), 6.0f);
}

__device__ __forceinline__ f32x16 mfma3(short8 a0, short8 a1, short8 a2,
                                        short8 b0, short8 b1, short8 b2){
  f32x16 c = {0,0,0,0,0,0,0,0,0,0,0,0,0,0,0,0};
  c = __builtin_amdgcn_mfma_f32_32x32x16_bf16(a0, b0, c, 0, 0, 0);
  c = __builtin_amdgcn_mfma_f32_32x32x16_bf16(a1, b1, c, 0, 0, 0);
  c = __builtin_amdgcn_mfma_f32_32x32x16_bf16(a2, b2, c, 0, 0, 0);
  return c;
}

// ae 16x16 A-frag offset for element (m,k): lane = ((k&31)>>3)*16 + (m&15)
__device__ __forceinline__ int ae16_off(int m, int k){
  return (m >> 4)*1024 + (k >> 5)*512 + (((k & 31) >> 3) << 7) + (m & 15)*8 + (k & 7);
}

// Flat, octet-vectorized prep: one thread = 8 contiguous k of one fragment
// row (2x float4 load + 8 cvt + 1x 16B store). Total 95040 octets.
// 32x32 B-frag: col=l&31, k=8*(l>>5)+j (+16*kf)   (verified r3-r19)
// 16x16 B-frag: col=l&15, k=8*(l>>4)+j (+32*kf)   (verified r2/r13/r18)
__global__ __launch_bounds__(512)
void prep_frags(const float* __restrict__ Qw, const float* __restrict__ Lw,
                const float* __restrict__ Mw, const float* __restrict__ Tw,
                const float* __restrict__ Ew, const float* __restrict__ Eb,
                const float* __restrict__ Qb, const float* __restrict__ Lb,
                const float* __restrict__ Mb, const float* __restrict__ Tb,
                unsigned short* __restrict__ ws)
{
  const int g = blockIdx.x*512 + threadIdx.x;
  if (g >= 95040) return;
  float v[8];
  #pragma unroll
  for (int j = 0; j < 8; ++j) v[j] = 0.f;

  if (g < 69120){                         // LWF: full tiles (e 0..31)
    int unit = g/192, o = g - unit*192;
    int s = unit/40, d = unit - s*40;
    int kf = o >> 6, l = o & 63;
    int kb = kf*16 + ((l >> 5) << 3);
    int n = d*DD + (l & 31);
    const float* W = Lw + (size_t)s*64000 + (size_t)n*DD;
    if (kb < DD){
      float4 x = *(const float4*)(W + kb);
      float4 y = *(const float4*)(W + kb + 4);
      v[0]=x.x; v[1]=x.y; v[2]=x.z; v[3]=x.w;
      v[4]=y.x; v[5]=y.y; v[6]=y.z; v[7]=y.w;
    } else {
      v[0] = Lb[(size_t)s*1600 + n];
    }
  } else if (g < 86400){                  // LWT: packed tails
    int gg = g - 69120;
    int unit = gg/192, o = gg - unit*192;
    int s = unit/10, tt = unit - s*10;
    int kf = o >> 6, l = o & 63;
    int kb = kf*16 + ((l >> 5) << 3);
    int c = l & 31;
    int n = (4*tt + (c >> 3))*DD + 32 + (c & 7);
    const float* W = Lw + (size_t)s*64000 + (size_t)n*DD;
    if (kb < DD){
      float4 x = *(const float4*)(W + kb);
      float4 y = *(const float4*)(W + kb + 4);
      v[0]=x.x; v[1]=x.y; v[2]=x.z; v[3]=x.w;
      v[4]=y.x; v[5]=y.y; v[6]=y.z; v[7]=y.w;
    } else {
      v[0] = Lb[(size_t)s*1600 + n];
    }
  } else if (g < 89856){                  // QW (+Eb+Qb at k=40, Ew at k=41)
    int gg = g - 86400;
    int s = gg/384, oo = gg - s*384;
    int et = oo/192, o = oo - et*192;
    int kf = o >> 6, l = o & 63;
    int kb = kf*16 + ((l >> 5) << 3);
    int jc = et*32 + (l & 31);
    if (jc < DD){
      if (kb < DD){
        const float* W = Qw + (size_t)s*1600 + (size_t)jc*DD;
        float4 x = *(const float4*)(W + kb);
        float4 y = *(const float4*)(W + kb + 4);
        v[0]=x.x; v[1]=x.y; v[2]=x.z; v[3]=x.w;
        v[4]=y.x; v[5]=y.y; v[6]=y.z; v[7]=y.w;
      } else {
        v[0] = Eb[s*DD + jc] + Qb[s*DD + jc];
        v[1] = Ew[s*DD + jc];
      }
    }
  } else if (g < 93312){                  // MW 16x16 B-frags (+Mb at k=40)
    int gg = g - 89856;
    int s = gg/384, oo = gg - s*384;
    int et = oo >> 7, r = oo & 127;
    int kf = r >> 6, l = r & 63;
    int kb = kf*32 + ((l >> 4) << 3);
    int e = et*16 + (l & 15);
    if (e < DD){
      if (kb < DD){
        const float* W = Mw + (size_t)s*1600 + (size_t)e*DD;
        float4 x = *(const float4*)(W + kb);
        float4 y = *(const float4*)(W + kb + 4);
        v[0]=x.x; v[1]=x.y; v[2]=x.z; v[3]=x.w;
        v[4]=y.x; v[5]=y.y; v[6]=y.z; v[7]=y.w;
      } else if (kb == DD){
        v[0] = Mb[s*DD + e];
      }
    }
  } else {                                // TW (+Tb at k=40)
    int gg = g - 93312;
    int t = gg/192, o = gg - t*192;
    int kf = o >> 6, l = o & 63;
    int kb = kf*16 + ((l >> 5) << 3);
    int a = t*32 + (l & 31);
    if (a < ANUM){
      if (kb < DD){
        const float* W = Tw + (size_t)a*DD;
        float4 x = *(const float4*)(W + kb);
        float4 y = *(const float4*)(W + kb + 4);
        v[0]=x.x; v[1]=x.y; v[2]=x.z; v[3]=x.w;
        v[4]=y.x; v[5]=y.y; v[6]=y.z; v[7]=y.w;
      } else {
        v[0] = Tb[a];
      }
    }
  }
  short8 sv;
  #pragma unroll
  for (int j = 0; j < 8; ++j) sv[j] = (short)f2bf(v[j]);
  *(short8*)(ws + (size_t)g*8) = sv;
}

// r19 base (best). r20 delta: in-loop barriers are lgkm-only (BAR_LDS) so the
// cross-step q/r prefetch loads ride across the barrier instead of draining
// at vmcnt(0) -- the compiler still emits counted vmcnt before first use.
__global__ __launch_bounds__(512)
void star_main(const int* __restrict__ X,
               const int* __restrict__ T1,
               const int* __restrict__ T2,
               const float* __restrict__ emb,
               const unsigned short* __restrict__ ws,
               float* __restrict__ out)
{
  __shared__ __align__(16) unsigned short pbuf[2][3072];  // p-state, 32x32 A-frag order
  __shared__ __align__(16) unsigned short aebf16[2][2048];// emb gather, 16x16 A-frag order
  __shared__ __align__(16) float hT[2][DD*36];            // h-state, [d][m]
  __shared__ __align__(16) float red[8][MB*RST2];         // tt partials per wave
  __shared__ int   aeidx[SLM1][MB];
  __shared__ float tvtab[SLM1][MB];

  const int tid = threadIdx.x;
  const int w = __builtin_amdgcn_readfirstlane(tid >> 6);
  const int l = tid & 63;
  const int col = l & 31, half = l >> 5;
  const int row0 = blockIdx.x * MB;

  // ---- prologue (full __syncthreads barriers; once, off the hot path) ----
  {
    unsigned int* p = (unsigned int*)&pbuf[0][0];
    for (int i = tid; i < 3072; i += 512) p[i] = 0u;
    unsigned int* a = (unsigned int*)&aebf16[0][0];
    for (int i = tid; i < 2048; i += 512) a[i] = 0u;
    float* rr = &red[0][0];
    for (int i = tid; i < 8*MB*RST2; i += 512) rr[i] = 0.f;  // C(0) sums zeros;
    // waves 6,7 never write tail cols -> their slices must stay zero forever
  }
  if (tid < MB*SLM1){
    int m = tid / SLM1, s = tid - m*SLM1;
    int r = row0 + m;
    aeidx[s][m] = X[(size_t)r*40 + s*4 + 3];
    tvtab[s][m] = (float)(T1[r*SLM1 + s]*8 + T2[r*SLM1 + s]);
  }
  __syncthreads();
  if (tid < MB){
    int off = 2*1024 + (tid + 32)*8;    // p-state: k=40 bias mult, k=41 tvec
    pbuf[0][off] = 0x3F80; pbuf[1][off] = 0x3F80;
    pbuf[0][off+1] = f2bf(tvtab[0][tid]);
    pbuf[1][off+1] = f2bf(tvtab[1][tid]);
    int o16 = ae16_off(tid, 40);        // ae 16-order bias
    aebf16[0][o16] = 0x3F80; aebf16[1][o16] = 0x3F80;
  }
  if (tid < 320){  // gather ae(0), 16-order
    int m = tid / 10, q4 = tid - m*10;
    float4 v4 = *(const float4*)(emb + (size_t)aeidx[0][m]*DD + q4*4);
    #pragma unroll
    for (int c2 = 0; c2 < 4; ++c2)
      aebf16[0][ae16_off(m, q4*4 + c2)] = f2bf(((const float*)&v4)[c2]);
  }
  __syncthreads();
  // A(0): p1(0) = relu6(0@Qw + t*Ew + Eb + Qb), waves 0,1
  if (w < 2){
    short8 a0 = ((const short8*)&pbuf[0][0])[l];
    short8 a1 = ((const short8*)&pbuf[0][1024])[l];
    short8 a2 = ((const short8*)&pbuf[0][2048])[l];
    const unsigned short* qwb = ws + WS_QW + w*1536;
    f32x16 c = mfma3(a0, a1, a2, ((const short8*)qwb)[l],
                     ((const short8*)(qwb+512))[l], ((const short8*)(qwb+1024))[l]);
    int j = w*32 + col;
    if (j < DD){
      int kf = j >> 4, kk = j & 15;
      #pragma unroll
      for (int r = 0; r < 16; ++r){
        int m = (r & 3) + ((r >> 2) << 3) + (half << 2);
        pbuf[1][kf*1024 + (m + ((kk >> 3) << 5))*8 + (kk & 7)] = f2bf(relu6f(c[r]));
      }
    }
  }
  __syncthreads();

  // cross-step prefetch regs: next step's BOTH pairs (d = w, w+8, w+16, w+24)
  short8 q00, q01, q02, q10, q11, q12;
  short8 r00, r01, r02, r10, r11, r12;

  for (int s = 0; s < SLM1; ++s){
    const int pcur = (s + 1) & 1;   // buffer holding p1(s)
    const int hrd  = s & 1;

    // ---- phase 1: B(s) (all waves, dual-stream) + A(s+1) (waves 6,7) ----
    float4 gv; int gm = 0, gq = 0;
    const bool dog = (s < 8) && (tid < 320);
    if (dog){
      gm = tid / 10; gq = tid - gm*10;
      gv = *(const float4*)(emb + (size_t)aeidx[s+1][gm]*DD + gq*4);
    }
    short8 pa0 = ((const short8*)&pbuf[pcur][0])[l];
    short8 pa1 = ((const short8*)&pbuf[pcur][1024])[l];
    short8 pa2 = ((const short8*)&pbuf[pcur][2048])[l];

    // T regs carry the tail / Qw triplet into the post-B sections
    short8 T0, T1r, T2r;

    if (s > 0){
      const float* hbase = &hT[hrd][half << 2];
      const unsigned short* lwf = ws + WS_LWF + (size_t)(s*40)*1536;

      // issue single (d=w+32) + tail/Qw loads NOW (hide under 2 pairs' compute)
      short8 S0, S1, S2;
      {
        const unsigned short* fS = lwf + (size_t)(32 + w)*1536;
        S0 = ((const short8*)fS)[l];
        S1 = ((const short8*)(fS + 512))[l];
        S2 = ((const short8*)(fS + 1024))[l];
        const size_t qs = (s < 8) ? (size_t)(s + 1) : (size_t)8;
        const unsigned short* fT = (w < 6)
            ? ws + WS_LWT + (size_t)(s*10 + w)*1536
            : ws + WS_QW + qs*3072 + (size_t)(w - 6)*1536;
        T0  = ((const short8*)fT)[l];
        T1r = ((const short8*)(fT + 512))[l];
        T2r = ((const short8*)(fT + 1024))[l];
      }

      f32x16 tt = {0,0,0,0,0,0,0,0,0,0,0,0,0,0,0,0};
      __builtin_amdgcn_s_setprio(1);
      // pair 0 (d = w, w+8) -- fragments prefetched LAST step
      {
        f32x16 ca = {0,0,0,0,0,0,0,0,0,0,0,0,0,0,0,0};
        f32x16 cb = {0,0,0,0,0,0,0,0,0,0,0,0,0,0,0,0};
        ca = __builtin_amdgcn_mfma_f32_32x32x16_bf16(pa0, q00, ca, 0, 0, 0);
        cb = __builtin_amdgcn_mfma_f32_32x32x16_bf16(pa0, q10, cb, 0, 0, 0);
        ca = __builtin_amdgcn_mfma_f32_32x32x16_bf16(pa1, q01, ca, 0, 0, 0);
        cb = __builtin_amdgcn_mfma_f32_32x32x16_bf16(pa1, q11, cb, 0, 0, 0);
        ca = __builtin_amdgcn_mfma_f32_32x32x16_bf16(pa2, q02, ca, 0, 0, 0);
        cb = __builtin_amdgcn_mfma_f32_32x32x16_bf16(pa2, q12, cb, 0, 0, 0);
        const float* hA = hbase + (w)*36;
        const float* hB = hbase + (8 + w)*36;
        #pragma unroll
        for (int g = 0; g < 4; ++g){
          f32x4 ha = *(const f32x4*)(hA + g*8);
          f32x4 hb = *(const f32x4*)(hB + g*8);
          #pragma unroll
          for (int q = 0; q < 4; ++q){
            tt[g*4+q] = fmaf(ha[q], relu6f(ca[g*4+q]), tt[g*4+q]);
            tt[g*4+q] = fmaf(hb[q], relu6f(cb[g*4+q]), tt[g*4+q]);
          }
        }
      }
      // pair 1 (d = w+16, w+24) -- also prefetched last step
      {
        f32x16 ca = {0,0,0,0,0,0,0,0,0,0,0,0,0,0,0,0};
        f32x16 cb = {0,0,0,0,0,0,0,0,0,0,0,0,0,0,0,0};
        ca = __builtin_amdgcn_mfma_f32_32x32x16_bf16(pa0, r00, ca, 0, 0, 0);
        cb = __builtin_amdgcn_mfma_f32_32x32x16_bf16(pa0, r10, cb, 0, 0, 0);
        ca = __builtin_amdgcn_mfma_f32_32x32x16_bf16(pa1, r01, ca, 0, 0, 0);
        cb = __builtin_amdgcn_mfma_f32_32x32x16_bf16(pa1, r11, cb, 0, 0, 0);
        ca = __builtin_amdgcn_mfma_f32_32x32x16_bf16(pa2, r02, ca, 0, 0, 0);
        cb = __builtin_amdgcn_mfma_f32_32x32x16_bf16(pa2, r12, cb, 0, 0, 0);
        const float* hA = hbase + (16 + w)*36;
        const float* hB = hbase + (24 + w)*36;
        #pragma unroll
        for (int g = 0; g < 4; ++g){
          f32x4 ha = *(const f32x4*)(hA + g*8);
          f32x4 hb = *(const f32x4*)(hB + g*8);
          #pragma unroll
          for (int q = 0; q < 4; ++q){
            tt[g*4+q] = fmaf(ha[q], relu6f(ca[g*4+q]), tt[g*4+q]);
            tt[g*4+q] = fmaf(hb[q], relu6f(cb[g*4+q]), tt[g*4+q]);
          }
        }
      }
      // single (d = w+32)
      {
        f32x16 c = mfma3(pa0, pa1, pa2, S0, S1, S2);
        const float* hb = hbase + (32 + w)*36;
        #pragma unroll
        for (int g = 0; g < 4; ++g){
          f32x4 hg = *(const f32x4*)(hb + g*8);
          #pragma unroll
          for (int q = 0; q < 4; ++q)
            tt[g*4+q] = fmaf(hg[q], relu6f(c[g*4+q]), tt[g*4+q]);
        }
      }
      __builtin_amdgcn_s_setprio(0);
      // commit full-tile partials (plain stores, per-wave slice)
      #pragma unroll
      for (int r = 0; r < 16; ++r){
        int m = (r & 3) + ((r >> 2) << 3) + (half << 2);
        red[w][m*RST2 + col] = tt[r];
      }
    }

    // cross-step prefetch for step s+1: BOTH pairs (ride across the lgkm-only
    // barrier; compiler emits counted vmcnt before first use next step)
    if (s < 8){
      const unsigned short* nl = ws + WS_LWF + (size_t)((s+1)*40)*1536;
      const unsigned short* n0 = nl + (size_t)w*1536;
      q00 = ((const short8*)n0)[l];
      q01 = ((const short8*)(n0 + 512))[l];
      q02 = ((const short8*)(n0 + 1024))[l];
      const unsigned short* n1 = nl + (size_t)(8 + w)*1536;
      q10 = ((const short8*)n1)[l];
      q11 = ((const short8*)(n1 + 512))[l];
      q12 = ((const short8*)(n1 + 1024))[l];
      const unsigned short* n2 = nl + (size_t)(16 + w)*1536;
      r00 = ((const short8*)n2)[l];
      r01 = ((const short8*)(n2 + 512))[l];
      r02 = ((const short8*)(n2 + 1024))[l];
      const unsigned short* n3 = nl + (size_t)(24 + w)*1536;
      r10 = ((const short8*)n3)[l];
      r11 = ((const short8*)(n3 + 512))[l];
      r12 = ((const short8*)(n3 + 1024))[l];
    }

    if (s > 0 && w < 6){
      // packed tails, waves 0-5 stride 6; first tile's triplet in T regs
      const unsigned short* lwt = ws + WS_LWT + (size_t)(s*10)*1536;
      f32x16 tacc = {0,0,0,0,0,0,0,0,0,0,0,0,0,0,0,0};
      {
        f32x16 c = mfma3(pa0, pa1, pa2, T0, T1r, T2r);
        int dt = 4*w + (col >> 3);
        const float* hb0 = &hT[hrd][dt*36 + (half << 2)];
        #pragma unroll
        for (int g = 0; g < 4; ++g){
          f32x4 hg = *(const f32x4*)(hb0 + g*8);
          #pragma unroll
          for (int q = 0; q < 4; ++q){
            float val = hg[q]*relu6f(c[g*4+q]);
            val += __shfl_xor(val, 8);
            val += __shfl_xor(val, 16);
            tacc[g*4+q] += val;
          }
        }
      }
      if (w < 4){
        const int t2 = w + 6;
        const unsigned short* ft = lwt + (size_t)t2*1536;
        short8 t0 = ((const short8*)ft)[l];
        short8 t1 = ((const short8*)(ft + 512))[l];
        short8 t2r = ((const short8*)(ft + 1024))[l];
        f32x16 c = mfma3(pa0, pa1, pa2, t0, t1, t2r);
        int dt = 4*t2 + (col >> 3);
        const float* hb = &hT[hrd][dt*36 + (half << 2)];
        #pragma unroll
        for (int g = 0; g < 4; ++g){
          f32x4 hg = *(const f32x4*)(hb + g*8);
          #pragma unroll
          for (int q = 0; q < 4; ++q){
            float val = hg[q]*relu6f(c[g*4+q]);
            val += __shfl_xor(val, 8);
            val += __shfl_xor(val, 16);
            tacc[g*4+q] += val;
          }
        }
      }
      if (col < 8){
        #pragma unroll
        for (int r = 0; r < 16; ++r){
          int m = (r & 3) + ((r >> 2) << 3) + (half << 2);
          red[w][m*RST2 + 32 + col] = tacc[r];
        }
      }
    } else if (w >= 6 && s < 8){
      // A(s+1) on waves 6,7: Qw triplet in T regs (s>0) or loaded inline (s==0)
      short8 Q0, Q1, Q2;
      if (s == 0){
        const unsigned short* qwb = ws + WS_QW + (size_t)(s+1)*3072 + (size_t)(w-6)*1536;
        Q0 = ((const short8*)qwb)[l];
        Q1 = ((const short8*)(qwb + 512))[l];
        Q2 = ((const short8*)(qwb + 1024))[l];
      } else {
        Q0 = T0; Q1 = T1r; Q2 = T2r;
      }
      f32x16 c = mfma3(pa0, pa1, pa2, Q0, Q1, Q2);
      int j = (w - 6)*32 + col;
      if (j < DD){
        int kf = j >> 4, kk = j & 15;
        #pragma unroll
        for (int r = 0; r < 16; ++r){
          int m = (r & 3) + ((r >> 2) << 3) + (half << 2);
          pbuf[s & 1][kf*1024 + (m + ((kk >> 3) << 5))*8 + (kk & 7)] = f2bf(relu6f(c[r]));
        }
      }
    }
    // late writes: ae(s+1) 16-order; tvec(s+2) into pbuf[s&1] k=41 slot
    if (dog){
      unsigned short* dst = &aebf16[(s+1) & 1][0];
      #pragma unroll
      for (int c2 = 0; c2 < 4; ++c2)
        dst[ae16_off(gm, gq*4 + c2)] = f2bf(((const float*)&gv)[c2]);
    }
    if (s <= 6 && tid < MB)
      pbuf[s & 1][2*1024 + (tid + 32)*8 + 1] = f2bf(tvtab[s+2][tid]);
    BAR_LDS();

    // ---- phase 2: C(s) on 6 waves via 16x16x32 MFMA ----
    if (w < 6){
      const int mt = (w >= 3) ? 1 : 0, et = w - mt*3;
      const int lr = l & 15, lg = l >> 4;
      const int e = et*16 + lr;
      const int mbase = mt*16 + (lg << 2);
      f32x4 c = {0.f, 0.f, 0.f, 0.f};
      if (e < DD){
        #pragma unroll
        for (int r = 0; r < 4; ++r){
          int m = mbase + r;
          float acc = red[0][m*RST2 + e];
          #pragma unroll
          for (int dp = 1; dp < 8; ++dp) acc += red[dp][m*RST2 + e];
          c[r] = acc;
        }
      }
      const unsigned short* ab = &aebf16[s & 1][mt*1024];
      short8 a0 = ((const short8*)ab)[l];
      short8 a1 = ((const short8*)(ab + 512))[l];
      const unsigned short* mwb = ws + WS_MW + (size_t)s*3072 + (size_t)et*1024;
      short8 b0 = ((const short8*)mwb)[l];
      short8 b1 = ((const short8*)(mwb + 512))[l];
      c = __builtin_amdgcn_mfma_f32_16x16x32_bf16(a0, b0, c, 0, 0, 0);
      c = __builtin_amdgcn_mfma_f32_16x16x32_bf16(a1, b1, c, 0, 0, 0);
      if (e < DD){
        f32x4 hv;
        #pragma unroll
        for (int r = 0; r < 4; ++r) hv[r] = relu6f(c[r]);
        *(f32x4*)&hT[(s+1) & 1][e*36 + mbase] = hv;   // one b128, m-contiguous
        if (s == SLM1-1){
          #pragma unroll
          for (int r = 0; r < 4; ++r){
            int m = mbase + r;
            int kf = e >> 4, kk = e & 15;   // final h -> pbuf[0] (dead p1(7))
            pbuf[0][kf*1024 + (m + ((kk >> 3) << 5))*8 + (kk & 7)] = f2bf(hv[r]);
          }
        }
      }
    }
    BAR_LDS();
  }

  // ---- epilogue: out = h@Tw^T + Tb via MFMA (h-frag in pbuf[0]) ----
  for (int t = w; t < 9; t += 8){
    short8 a0 = ((const short8*)&pbuf[0][0])[l];
    short8 a1 = ((const short8*)&pbuf[0][1024])[l];
    short8 a2 = ((const short8*)&pbuf[0][2048])[l];
    const unsigned short* twb = ws + WS_TW + (size_t)t*1536;
    f32x16 c = mfma3(a0, a1, a2, ((const short8*)twb)[l],
                     ((const short8*)(twb+512))[l], ((const short8*)(twb+1024))[l]);
    int a = t*32 + col;
    if (a < ANUM){
      #pragma unroll
      for (int r = 0; r < 16; ++r){
        int m = (r & 3) + ((r >> 2) << 3) + (half << 2);
        out[(size_t)(row0 + m)*ANUM + a] = c[r];
      }
    }
  }
}

extern "C" void kernel_launch(void* const* d_in, const int* in_sizes, int n_in,
                              void* d_out, int out_size, void* d_ws, size_t ws_size,
                              hipStream_t stream) {
  const int*   X  = (const int*)  d_in[0];
  const int*   T1 = (const int*)  d_in[1];
  const int*   T2 = (const int*)  d_in[2];
  const float* Ew = (const float*)d_in[3];
  const float* Eb = (const float*)d_in[4];
  const float* Qw = (const float*)d_in[5];
  const float* Qb = (const float*)d_in[6];
  const float* Lw = (const float*)d_in[7];
  const float* Lb = (const float*)d_in[8];
  const float* Mw = (const float*)d_in[9];
  const float* Mb = (const float*)d_in[10];
  const float* Tw = (const float*)d_in[11];
  const float* Tb = (const float*)d_in[12];
  const float* em = (const float*)d_in[13];
  unsigned short* ws = (unsigned short*)d_ws;
  float* out = (float*)d_out;

  prep_frags<<<dim3(186), dim3(512), 0, stream>>>(Qw, Lw, Mw, Tw, Ew, Eb, Qb,
                                                  Lb, Mb, Tb, ws);
  star_main<<<dim3(8192 / MB), dim3(512), 0, stream>>>(X, T1, T2, em, ws, out);
}